// Round 1
// baseline (501.995 us; speedup 1.0000x reference)
//
#include <hip/hip_runtime.h>

// Problem constants (from reference): B=256, L=512, D=768, 54 outputs/row.
#define BATCH 256
#define SEQ   512
#define DIM   768
#define D4    (DIM / 4)   // 192 float4 per row
#define NOUT  54

#define STRIPS        8                 // strips per batch
#define ROWS_PER_STRIP (SEQ / STRIPS)   // 64
#define NPART         (BATCH * STRIPS)  // 2048 partial vectors

// ---------------------------------------------------------------------------
// Kernel 1: masked partial row-sum.
// grid = 2048 (batch b = bid>>3, strip s = bid&7), block = 256 = 4 waves.
// Each wave owns 16 CONSECUTIVE sequence rows (sequential 48 KB window ->
// good DRAM page locality, no scatter-gather), skips masked-out rows with a
// wave-uniform branch (mask broadcast via __shfl), accumulates 768 floats in
// 3 float4 regs/lane, 4-wave LDS reduce, writes one 3 KB partial + count.
// ~40 VGPR, 12.3 KiB LDS -> 8 blocks/CU = 32 waves/CU (full occupancy).
// ---------------------------------------------------------------------------
__global__ __launch_bounds__(256) void pool_partial_kernel(
    const float* __restrict__ fh, const int* __restrict__ mask,
    float* __restrict__ part, int* __restrict__ cnt)
{
    const int bid  = blockIdx.x;
    const int b    = bid >> 3;
    const int s    = bid & 7;
    const int tid  = threadIdx.x;
    const int lane = tid & 63;
    const int wave = tid >> 6;   // 0..3

    const int row0 = s * ROWS_PER_STRIP + wave * 16;

    // lanes 0..15 hold the 16 mask values for this wave's rows
    int m = 0;
    if (lane < 16) m = mask[b * SEQ + row0 + lane];

    const float4* fh4 = (const float4*)fh + ((size_t)b * SEQ + row0) * D4;

    float4 a0 = make_float4(0.f, 0.f, 0.f, 0.f);
    float4 a1 = a0, a2 = a0;

    #pragma unroll
    for (int r = 0; r < 16; ++r) {
        if (__shfl(m, r) != 0) {               // wave-uniform branch
            const float4* rp = fh4 + (size_t)r * D4;
            float4 x0 = rp[lane], x1 = rp[lane + 64], x2 = rp[lane + 128];
            a0.x += x0.x; a0.y += x0.y; a0.z += x0.z; a0.w += x0.w;
            a1.x += x1.x; a1.y += x1.y; a1.z += x1.z; a1.w += x1.w;
            a2.x += x2.x; a2.y += x2.y; a2.z += x2.z; a2.w += x2.w;
        }
    }

    // active-row count for this wave's 16 rows (lanes >=16 contribute 0)
    const int myc = __popcll(__ballot(m != 0));

    // 4-wave LDS reduce
    __shared__ float4 red[4][D4];   // 12 KiB
    __shared__ int    wc[4];
    red[wave][lane]       = a0;
    red[wave][lane + 64]  = a1;
    red[wave][lane + 128] = a2;
    if (lane == 0) wc[wave] = myc;
    __syncthreads();

    if (tid < D4) {
        float4 v0 = red[0][tid], v1 = red[1][tid];
        float4 v2 = red[2][tid], v3 = red[3][tid];
        float4 acc;
        acc.x = (v0.x + v1.x) + (v2.x + v3.x);
        acc.y = (v0.y + v1.y) + (v2.y + v3.y);
        acc.z = (v0.z + v1.z) + (v2.z + v3.z);
        acc.w = (v0.w + v1.w) + (v2.w + v3.w);
        ((float4*)part)[(size_t)bid * D4 + tid] = acc;
    }
    if (tid == 0) cnt[bid] = wc[0] + wc[1] + wc[2] + wc[3];
}

// ---------------------------------------------------------------------------
// Kernel 2: combine 8 partials per batch, scale by 1/n, 54 head projections.
// grid = 256, block = 256 = 4 waves. Weights (166 KB) stay L2-resident.
// ---------------------------------------------------------------------------
__global__ __launch_bounds__(256) void head_kernel(
    const float* __restrict__ part, const int* __restrict__ cnt,
    const float* __restrict__ W13, const float* __restrict__ b13,
    const float* __restrict__ W14, const float* __restrict__ b14,
    float* __restrict__ out)
{
    const int b    = blockIdx.x;
    const int tid  = threadIdx.x;
    const int lane = tid & 63;
    const int wave = tid >> 6;

    __shared__ float pooled[DIM];   // UNscaled sum; scale folded into epilogue
    __shared__ int   ns;

    if (tid < 8) {
        int n = cnt[b * 8 + tid];
        n += __shfl_down(n, 4);
        n += __shfl_down(n, 2);
        n += __shfl_down(n, 1);
        if (tid == 0) ns = n;
    }

    if (tid < D4) {
        const float4* p4 = (const float4*)part + (size_t)b * 8 * D4;
        float4 acc = make_float4(0.f, 0.f, 0.f, 0.f);
        #pragma unroll
        for (int s = 0; s < 8; ++s) {
            float4 v = p4[(size_t)s * D4 + tid];
            acc.x += v.x; acc.y += v.y; acc.z += v.z; acc.w += v.w;
        }
        ((float4*)pooled)[tid] = acc;
    }
    __syncthreads();

    const float inv = 1.0f / (float)ns;

    for (int o = wave; o < NOUT; o += 4) {
        const float* Wrow = (o < 52) ? (W13 + (size_t)o * DIM)
                                     : (W14 + (size_t)(o - 52) * DIM);
        const float bias  = (o < 52) ? b13[o] : b14[o - 52];
        float acc = 0.f;
        #pragma unroll
        for (int j = 0; j < 12; ++j) {
            const int d = lane + 64 * j;
            acc = fmaf(pooled[d], Wrow[d], acc);
        }
        for (int off = 32; off; off >>= 1) acc += __shfl_down(acc, off);
        if (lane == 0) out[(size_t)b * NOUT + o] = fmaf(acc, inv, bias);
    }
}

// ---------------------------------------------------------------------------
// Fallback: previous best fused single-kernel path (used only if the
// workspace is somehow smaller than 6.3 MB — never observed; fills show
// ws ~1.5 GiB).
// ---------------------------------------------------------------------------
__global__ __launch_bounds__(1024) void bow_fused_kernel(
    const float* __restrict__ fh, const int* __restrict__ mask,
    const float* __restrict__ W13, const float* __restrict__ b13,
    const float* __restrict__ W14, const float* __restrict__ b14,
    float* __restrict__ out)
{
    const int b    = blockIdx.x;
    const int tid  = threadIdx.x;
    const int lane = tid & 63;
    const int wave = tid >> 6;   // 0..15

    __shared__ unsigned long long balls[8];
    __shared__ int   list[SEQ];
    __shared__ float pooled[DIM];

    int my_m = 0;
    if (wave < 8) {
        my_m = mask[b * SEQ + tid];
        unsigned long long bl = __ballot(my_m != 0);
        if (lane == 0) balls[wave] = bl;
    }
    __syncthreads();

    int n = 0;
    #pragma unroll
    for (int w = 0; w < 8; ++w) n += __popcll(balls[w]);

    if (wave < 8 && my_m != 0) {
        int off = 0;
        for (int w = 0; w < wave; ++w) off += __popcll(balls[w]);
        const unsigned long long bl = balls[wave];
        list[off + __popcll(bl & ((1ull << lane) - 1))] = tid;
    }
    __syncthreads();

    const float4* fh4 = (const float4*)fh + (size_t)b * SEQ * D4;

    float4 a0 = make_float4(0.f, 0.f, 0.f, 0.f);
    float4 a1 = a0, a2 = a0;

    int i = wave;
    for (; i + 16 < n; i += 32) {
        const float4* r0 = fh4 + (size_t)list[i]      * D4;
        const float4* r1 = fh4 + (size_t)list[i + 16] * D4;
        float4 x0 = r0[lane], x1 = r0[lane + 64], x2 = r0[lane + 128];
        float4 y0 = r1[lane], y1 = r1[lane + 64], y2 = r1[lane + 128];
        a0.x += x0.x + y0.x; a0.y += x0.y + y0.y;
        a0.z += x0.z + y0.z; a0.w += x0.w + y0.w;
        a1.x += x1.x + y1.x; a1.y += x1.y + y1.y;
        a1.z += x1.z + y1.z; a1.w += x1.w + y1.w;
        a2.x += x2.x + y2.x; a2.y += x2.y + y2.y;
        a2.z += x2.z + y2.z; a2.w += x2.w + y2.w;
    }
    if (i < n) {
        const float4* r0 = fh4 + (size_t)list[i] * D4;
        float4 x0 = r0[lane], x1 = r0[lane + 64], x2 = r0[lane + 128];
        a0.x += x0.x; a0.y += x0.y; a0.z += x0.z; a0.w += x0.w;
        a1.x += x1.x; a1.y += x1.y; a1.z += x1.z; a1.w += x1.w;
        a2.x += x2.x; a2.y += x2.y; a2.z += x2.z; a2.w += x2.w;
    }

    __shared__ float4 red[16][D4];
    red[wave][lane]       = a0;
    red[wave][lane + 64]  = a1;
    red[wave][lane + 128] = a2;
    __syncthreads();

    const float inv = 1.0f / (float)n;
    if (tid < D4) {
        float4 acc = make_float4(0.f, 0.f, 0.f, 0.f);
        #pragma unroll
        for (int w = 0; w < 16; ++w) {
            float4 v = red[w][tid];
            acc.x += v.x; acc.y += v.y; acc.z += v.z; acc.w += v.w;
        }
        ((float4*)pooled)[tid] =
            make_float4(acc.x * inv, acc.y * inv, acc.z * inv, acc.w * inv);
    }
    __syncthreads();

    for (int o = wave; o < NOUT; o += 16) {
        const float* Wrow = (o < 52) ? (W13 + (size_t)o * DIM)
                                     : (W14 + (size_t)(o - 52) * DIM);
        const float bias  = (o < 52) ? b13[o] : b14[o - 52];
        float acc = 0.f;
        #pragma unroll
        for (int j = 0; j < 12; ++j) {
            const int d = lane + 64 * j;
            acc = fmaf(pooled[d], Wrow[d], acc);
        }
        for (int off = 32; off; off >>= 1) acc += __shfl_down(acc, off);
        if (lane == 0) out[(size_t)b * NOUT + o] = acc + bias;
    }
}

// ---------------------------------------------------------------------------
// Inputs (setup_inputs order):
//   0: final_hidden  [256,512,768] f32   1: attention_mask [256,512] i32
//   2: W13 [13,4,768] f32               3: b13 [13,4] f32
//   4: W14 [2,768] f32                  5: b14 [2] f32
// Output: [256,54] f32.
// Workspace: part = NPART*768 f32 (6.29 MB) + cnt = NPART i32 (8 KB).
// Both fully written by kernel 1 before kernel 2 reads -> safe under
// per-iteration workspace poisoning; kernel boundary gives device-wide
// visibility (cross-XCD coherent).
// ---------------------------------------------------------------------------
extern "C" void kernel_launch(void* const* d_in, const int* in_sizes, int n_in,
                              void* d_out, int out_size, void* d_ws, size_t ws_size,
                              hipStream_t stream) {
    const float* fh   = (const float*)d_in[0];
    const int*   mask = (const int*)d_in[1];
    const float* W13  = (const float*)d_in[2];
    const float* b13  = (const float*)d_in[3];
    const float* W14  = (const float*)d_in[4];
    const float* b14  = (const float*)d_in[5];
    float*       out  = (float*)d_out;

    const size_t part_bytes = (size_t)NPART * DIM * sizeof(float);
    const size_t cnt_bytes  = (size_t)NPART * sizeof(int);

    if (d_ws != nullptr && ws_size >= part_bytes + cnt_bytes) {
        float* part = (float*)d_ws;
        int*   cnt  = (int*)((char*)d_ws + part_bytes);

        pool_partial_kernel<<<dim3(NPART), dim3(256), 0, stream>>>(
            fh, mask, part, cnt);
        head_kernel<<<dim3(BATCH), dim3(256), 0, stream>>>(
            part, cnt, W13, b13, W14, b14, out);
    } else {
        bow_fused_kernel<<<dim3(BATCH), dim3(1024), 0, stream>>>(
            fh, mask, W13, b13, W14, b14, out);
    }
}